// Round 6
// baseline (85.519 us; speedup 1.0000x reference)
//
#include <hip/hip_runtime.h>

// Problem constants (fixed by setup_inputs)
constexpr int B   = 256;
constexpr int IN  = 256;
constexpr int OUT = 512;
constexpr double EPSD = 1e-7;

typedef unsigned long long ull;

// ---------------------------------------------------------------------------
// Workspace:
//   RXD [B][IN]   f64 (512 KB)  1/(x+eps)
//   PART[8][IN]   f64 (16 KB)   partial colsums of x
//   XT  [IN][B]   f32 (256 KB)  x transposed
//   TT  [OUT][B]  f32 (512 KB)  t transposed
//   WT  [OUT][IN] f32 (512 KB)  w transposed
// ---------------------------------------------------------------------------

__global__ __launch_bounds__(256) void k_setup(const float* __restrict__ x,
        const float* __restrict__ t, const float* __restrict__ w,
        double* __restrict__ rxd, double* __restrict__ part,
        float* __restrict__ xt, float* __restrict__ tt, float* __restrict__ wt) {
    const int tid = threadIdx.x;
    const int blk = blockIdx.x;
    if (blk < 32) {                          // RXD: 8 b-rows per block, coalesced
        const int b0 = blk * 8;
        #pragma unroll
        for (int k = 0; k < 8; ++k)
            rxd[(b0 + k) * IN + tid] = 1.0 / ((double)x[(b0 + k) * IN + tid] + EPSD);
    } else if (blk < 40) {                   // partial colsums: 32 b-rows per block
        const int j = blk - 32, b0 = j * 32;
        double s0 = 0, s1 = 0, s2 = 0, s3 = 0;
        #pragma unroll
        for (int k = 0; k < 32; k += 4) {
            s0 += (double)x[(b0 + k + 0) * IN + tid];
            s1 += (double)x[(b0 + k + 1) * IN + tid];
            s2 += (double)x[(b0 + k + 2) * IN + tid];
            s3 += (double)x[(b0 + k + 3) * IN + tid];
        }
        part[j * IN + tid] = (s0 + s1) + (s2 + s3);
    } else {                                 // tiled 64x64 transposes
        __shared__ float tile[64][65];
        const int c  = tid & 63;
        const int r4 = tid >> 6;             // 0..3
        const float* src; float* dst; int scols, srows_t0, scols_t0, dcols;
        if (blk < 56) {        // XT: x(256x256) -> [IN][B], 16 tiles
            const int tl = blk - 40;
            src = x;  dst = xt;  scols = IN; dcols = B;
            srows_t0 = (tl >> 2) * 64;  scols_t0 = (tl & 3) * 64;
        } else if (blk < 88) { // TT: t(256x512) -> [OUT][B], 32 tiles
            const int tl = blk - 56;
            src = t;  dst = tt;  scols = OUT; dcols = B;
            srows_t0 = (tl >> 3) * 64;  scols_t0 = (tl & 7) * 64;
        } else {               // WT: w(256x512) -> [OUT][IN], 32 tiles
            const int tl = blk - 88;
            src = w;  dst = wt;  scols = OUT; dcols = IN;
            srows_t0 = (tl >> 3) * 64;  scols_t0 = (tl & 7) * 64;
        }
        #pragma unroll
        for (int k = 0; k < 16; ++k) {
            const int r = r4 + k * 4;
            tile[r][c] = src[(srows_t0 + r) * scols + scols_t0 + c];   // coalesced
        }
        __syncthreads();
        #pragma unroll
        for (int k = 0; k < 16; ++k) {
            const int r = r4 + k * 4;
            dst[(size_t)(scols_t0 + r) * dcols + srows_t0 + c] = tile[c][r];  // coalesced
        }
    }
}

// ---------------------------------------------------------------------------
// Merged main kernel: block = o-pair (2*blk, 2*blk+1), 512 threads.
//   Every rxd/xt element is loaded ONCE and applied to BOTH o's (8 chains).
//   All global accesses coalesced via XT/TT/WT.
// ---------------------------------------------------------------------------
__global__ __launch_bounds__(512, 2) void k_main(const float* __restrict__ wt,
        const float* __restrict__ tt, const double* __restrict__ rxd,
        const double* __restrict__ part, const float* __restrict__ xt,
        float* __restrict__ out) {
    const int tid  = threadIdx.x;
    const int half = tid >> 8;          // o-index within pair (stage/finish roles)
    const int j    = tid & 255;
    const int o0   = blockIdx.x * 2;
    const int o    = o0 + half;

    __shared__ double tc[2][B];         // staged t columns (f64)        4 KB
    __shared__ double rcs[IN];          // 1/colsum per i (o-indep)      2 KB
    __shared__ double rp[2][4][IN];     // rel partials [o][bq][i]      16 KB
    __shared__ double rc[2][IN];        // rel columns                   4 KB
    __shared__ ull    keys[2][4][B];    // argmax keys [o][iq][b]       16 KB
    __shared__ ull    swv[2][4];        // per-wave warg keys

    // --- stage t column (coalesced via TT); w-argmax (coalesced via WT) ---
    tc[half][j] = (double)tt[(size_t)o * B + j];
    if (tid < 256) {                    // 1/colsum (shared by both o)
        double ps = 0.0;
        #pragma unroll
        for (int k = 0; k < 8; ++k) ps += part[k * IN + j];
        rcs[j] = 1.0 / ps;
    }
    {
        float wv = wt[(size_t)o * IN + j];
        ull key = ((ull)__float_as_uint(wv) << 8) | (unsigned)(255 - j);
        #pragma unroll
        for (int off = 32; off; off >>= 1) {
            ull v = __shfl_down(key, off);
            key = v > key ? v : key;
        }
        if ((tid & 63) == 0) swv[half][(tid >> 6) & 3] = key;
    }
    __syncthreads();
    const int warg_o = [&]{
        ull wk = swv[half][0];
        #pragma unroll
        for (int k = 1; k < 4; ++k) { ull v = swv[half][k]; wk = v > wk ? v : wk; }
        return 255 - (int)(wk & 0xFFull);
    }();

    // --- phase 1: rel partials; thread = (i-pair, b-quarter), BOTH o's ---
    {
        const int i0 = (tid & 127) * 2;
        const int bq = tid >> 7;                    // 0..3
        const double* __restrict__ t0c  = tc[0] + bq * 64;
        const double* __restrict__ t1c  = tc[1] + bq * 64;
        const double* __restrict__ base = rxd + (size_t)(bq * 64) * IN + i0;
        double a0 = 0, a1 = 0, a2 = 0, a3 = 0;      // o0 chains
        double c0 = 0, c1 = 0, c2 = 0, c3 = 0;      // o1 chains
        #pragma unroll 8
        for (int k = 0; k < 64; k += 2) {
            double2 r0 = *(const double2*)(base + (size_t)k * IN);
            double2 r1 = *(const double2*)(base + (size_t)(k + 1) * IN);
            double ta0 = t0c[k], ta1 = t0c[k + 1];
            double tb0 = t1c[k], tb1 = t1c[k + 1];
            a0 += fmin(ta0 * r0.x, 1.0);
            a1 += fmin(ta0 * r0.y, 1.0);
            a2 += fmin(ta1 * r1.x, 1.0);
            a3 += fmin(ta1 * r1.y, 1.0);
            c0 += fmin(tb0 * r0.x, 1.0);
            c1 += fmin(tb0 * r0.y, 1.0);
            c2 += fmin(tb1 * r1.x, 1.0);
            c3 += fmin(tb1 * r1.y, 1.0);
        }
        rp[0][bq][i0]     = a0 + a2;
        rp[0][bq][i0 + 1] = a1 + a3;
        rp[1][bq][i0]     = c0 + c2;
        rp[1][bq][i0 + 1] = c1 + c3;
    }
    __syncthreads();
    // combine: 512 threads cover both o's
    rc[half][j] = ((rp[half][0][j] + rp[half][1][j]) +
                   (rp[half][2][j] + rp[half][3][j])) * rcs[j];
    __syncthreads();

    // --- phase 2: argmax keys; thread = (b-pair, i-quarter), BOTH o's ---
    {
        const int b0 = (tid & 127) * 2;
        const int iq = tid >> 7;                    // 0..3
        const double* __restrict__ r0c = rc[0];
        const double* __restrict__ r1c = rc[1];
        double mA0 = -1.0, mA1 = -1.0, mB0 = -1.0, mB1 = -1.0;   // o0
        double nA0 = -1.0, nA1 = -1.0, nB0 = -1.0, nB1 = -1.0;   // o1
        #pragma unroll 8
        for (int i = iq * 64; i < iq * 64 + 64; i += 2) {
            float2 x0 = *(const float2*)&xt[(size_t)i * B + b0];
            float2 x1 = *(const float2*)&xt[(size_t)(i + 1) * B + b0];
            const long long e0 = (long long)(255 - i), e1 = (long long)(255 - (i + 1));
            double s;
            s = (double)x0.x * r0c[i];
            mA0 = fmax(mA0, __longlong_as_double((__double_as_longlong(s) & ~0xFFll) | e0));
            s = (double)x0.y * r0c[i];
            mB0 = fmax(mB0, __longlong_as_double((__double_as_longlong(s) & ~0xFFll) | e0));
            s = (double)x1.x * r0c[i + 1];
            mA1 = fmax(mA1, __longlong_as_double((__double_as_longlong(s) & ~0xFFll) | e1));
            s = (double)x1.y * r0c[i + 1];
            mB1 = fmax(mB1, __longlong_as_double((__double_as_longlong(s) & ~0xFFll) | e1));
            s = (double)x0.x * r1c[i];
            nA0 = fmax(nA0, __longlong_as_double((__double_as_longlong(s) & ~0xFFll) | e0));
            s = (double)x0.y * r1c[i];
            nB0 = fmax(nB0, __longlong_as_double((__double_as_longlong(s) & ~0xFFll) | e0));
            s = (double)x1.x * r1c[i + 1];
            nA1 = fmax(nA1, __longlong_as_double((__double_as_longlong(s) & ~0xFFll) | e1));
            s = (double)x1.y * r1c[i + 1];
            nB1 = fmax(nB1, __longlong_as_double((__double_as_longlong(s) & ~0xFFll) | e1));
        }
        keys[0][iq][b0]     = (ull)__double_as_longlong(fmax(mA0, mA1));
        keys[0][iq][b0 + 1] = (ull)__double_as_longlong(fmax(mB0, mB1));
        keys[1][iq][b0]     = (ull)__double_as_longlong(fmax(nA0, nA1));
        keys[1][iq][b0 + 1] = (ull)__double_as_longlong(fmax(nB0, nB1));
    }
    __syncthreads();

    // --- finish: thread (half, j) handles (o, b=j) ---
    {
        const int b = j;
        ull mk = keys[half][0][b];
        #pragma unroll
        for (int k = 1; k < 4; ++k) { ull v = keys[half][k][b]; mk = v > mk ? v : mk; }
        const int ia = 255 - (int)(mk & 0xFFull);

        float* __restrict__ out0 = out;
        float* __restrict__ out1 = out + (size_t)B * OUT;
        out0[b * OUT + o] = xt[(size_t)ia * B + b] * wt[(size_t)o * IN + ia];

        const int iw = (tc[half][b] > 0.0) ? warg_o : 0;
        out1[b * OUT + o] = xt[(size_t)iw * B + b] * wt[(size_t)o * IN + iw];
    }
}

// ---------------------------------------------------------------------------
extern "C" void kernel_launch(void* const* d_in, const int* in_sizes, int n_in,
                              void* d_out, int out_size, void* d_ws, size_t ws_size,
                              hipStream_t stream) {
    const float* x = (const float*)d_in[0];   // (B, IN)
    const float* w = (const float*)d_in[1];   // (IN, OUT)
    const float* t = (const float*)d_in[2];   // (B, OUT)
    float* out = (float*)d_out;               // 2 * B * OUT floats

    double* dws  = (double*)d_ws;
    double* RXD  = dws;                             // B*IN doubles  (512 KB)
    double* PART = RXD + (size_t)B * IN;            // 8*IN doubles  (16 KB)
    float*  XT   = (float*)(PART + 8 * IN);         // IN*B floats   (256 KB)
    float*  TT   = XT + (size_t)IN * B;             // OUT*B floats  (512 KB)
    float*  WT   = TT + (size_t)OUT * B;            // OUT*IN floats (512 KB)

    k_setup<<<120, 256, 0, stream>>>(x, t, w, RXD, PART, XT, TT, WT);
    k_main<<<OUT / 2, 512, 0, stream>>>(WT, TT, RXD, PART, XT, out);
}